// Round 12
// baseline (310.846 us; speedup 1.0000x reference)
//
#include <hip/hip_runtime.h>
#include <math.h>
#include <stdint.h>

// TreeLSTM, 32 complete binary trees depth 10, heap order, d=128.
// R17: phase-cost model (~4-5us per barrier phase at low occupancy) says the
//      hidden ~97us non-fused6 residue is dominated by tail_k (~9 phases, 32
//      blocks, own launch + weight reloads) running SERIALLY after fused6.
//      Fix: last-block-per-tree runs the tail INLINE (atomicAdd counter +
//      __threadfence release/acquire, split-K pattern): tail overlaps other
//      trees' round-2 blocks, reuses live aW/bU/bias regs + dead LDS, 5
//      phases instead of 9, one launch fewer. prep_k zeroes counters.

#define NTREES 32
#define MTREE 2047
#define NNODES (NTREES * MTREE)   // 65504

typedef __attribute__((ext_vector_type(8))) short bf16x8;
typedef __attribute__((ext_vector_type(4))) float f32x4;

__device__ __forceinline__ float sigmoidf_(float x) {
    return 1.0f / (1.0f + __expf(-x));
}
__device__ __forceinline__ float tanhf_(float x) {
    x = fminf(fmaxf(x, -10.0f), 10.0f);
    float e = __expf(2.0f * x);
    return (e - 1.0f) / (e + 1.0f);
}
__device__ __forceinline__ float bf2f(uint16_t b) {
    union { uint32_t u; float f; } v; v.u = ((uint32_t)b) << 16; return v.f;
}
__device__ __forceinline__ uint32_t cvtpk(float lo, float hi) {
    uint32_t r;
    asm("v_cvt_pk_bf16_f32 %0, %1, %2" : "=v"(r) : "v"(lo), "v"(hi));
    return r;
}
__device__ __forceinline__ uint16_t f2bf1(float f) {
    return (uint16_t)cvtpk(f, f);
}
__device__ __forceinline__ uint4 pack_bf8(float4 a, float4 b) {
    uint4 r;
    r.x = cvtpk(a.x, a.y); r.y = cvtpk(a.z, a.w);
    r.z = cvtpk(b.x, b.y); r.w = cvtpk(b.z, b.w);
    return r;
}

// raw workgroup barrier: LDS visibility only; global ops stay in flight
__device__ __forceinline__ void lds_barrier() {
    asm volatile("s_waitcnt lgkmcnt(0)" ::: "memory");
    __builtin_amdgcn_s_barrier();
    __builtin_amdgcn_sched_barrier(0);
}

// Swizzled LDS: bf16 rows of 128 (16 chunks of 16B), XOR by row&7.
#define SWZ(row, chunk) ((row) * 128 + (((chunk) ^ ((row) & 7)) * 8))
// f32 scalar c-buffer: float-level XOR
#define CIDX(row, col) ((row) * 128 + ((col) ^ (((row) & 7) << 2)))
// f32 float4-write buffer: 16B-chunk XOR
#define CAX(row, col) ((row) * 128 + (((((col) >> 2) ^ (((row) & 7) << 2)) & 31) << 2) + ((col) & 3))

__device__ __forceinline__ void hwr(uint16_t* buf, int row, int colf, float v) {
    buf[row * 128 + (((colf >> 3) ^ (row & 7)) * 8) + (colf & 7)] = f2bf1(v);
}

__device__ __forceinline__ void wx_unpack(ushort4 g, float o[4]) {
    o[0] = bf2f(g.x); o[1] = bf2f(g.y); o[2] = bf2f(g.z); o[3] = bf2f(g.w);
}

__device__ __forceinline__ void gate_epi(const f32x4 acc[4], const float wxj[2][4],
                                         const float cch[4], float hv[2], float cn[2]) {
    float fc[4];
#pragma unroll
    for (int r = 0; r < 4; ++r)
        fc[r] = sigmoidf_(acc[3][r] + wxj[r >> 1][3]) * cch[r];
#pragma unroll
    for (int j = 0; j < 2; ++j) {
        float ip = acc[0][2 * j] + acc[0][2 * j + 1] + wxj[j][0];
        float op = acc[1][2 * j] + acc[1][2 * j + 1] + wxj[j][1];
        float up = acc[2][2 * j] + acc[2][2 * j + 1] + wxj[j][2];
        cn[j] = sigmoidf_(ip) * tanhf_(up) + fc[2 * j] + fc[2 * j + 1];
        hv[j] = sigmoidf_(op) * tanhf_(cn[j]);
    }
}

// ---------------------------------------------------------------------------
__global__ __launch_bounds__(128) void prep_k(const float* __restrict__ Wiou,
                                              const float* __restrict__ Wf,
                                              const float* __restrict__ Uiou,
                                              const float* __restrict__ Uf,
                                              const float* __restrict__ biou,
                                              const float* __restrict__ bf,
                                              uint16_t* __restrict__ WT,
                                              uint16_t* __restrict__ UT,
                                              float* __restrict__ biasS,
                                              int* __restrict__ ctr) {
    int n = blockIdx.x, k = threadIdx.x;
    if (n < 512) {
        WT[n * 128 + k] = f2bf1(n < 384 ? Wiou[k * 384 + n] : Wf[k * 128 + (n - 384)]);
    } else if (n < 1024) {
        int m = n - 512;
        UT[m * 128 + k] = f2bf1(m < 384 ? Uiou[k * 384 + m] : Uf[k * 128 + (m - 384)]);
    } else {
#pragma unroll
        for (int r = 0; r < 4; ++r) {
            int j = r * 128 + k;
            biasS[j] = j < 384 ? biou[j] : bf[j - 384];
        }
        if (k < NTREES) ctr[k] = 0;
    }
}

// ---------------------------------------------------------------------------
__device__ __forceinline__ void load_bU(const uint16_t* __restrict__ UT, bf16x8 bU[4][4]) {
    const int tid = threadIdx.x;
    const int w = tid >> 6, lane = tid & 63, q = lane >> 4, l15 = lane & 15;
#pragma unroll
    for (int s = 0; s < 4; ++s) {
        int row = (w + s * 8) * 16 + l15;
#pragma unroll
        for (int kc = 0; kc < 4; ++kc)
            bU[s][kc] = *(const bf16x8*)(UT + (size_t)row * 128 + kc * 32 + q * 8);
    }
}

template<int NCT>
__device__ __forceinline__ void matvec_lds(const uint16_t* __restrict__ H,
                                           const bf16x8 bU[4][4],
                                           f32x4 acc[NCT][4], int l15, int q) {
#pragma unroll
    for (int ct = 0; ct < NCT; ++ct) {
        bf16x8 a[4];
#pragma unroll
        for (int kc = 0; kc < 4; ++kc)
            a[kc] = *(const bf16x8*)&H[SWZ(ct * 16 + l15, kc * 4 + q)];
#pragma unroll
        for (int s = 0; s < 4; ++s)
#pragma unroll
            for (int kc = 0; kc < 4; ++kc)
                acc[ct][s] = __builtin_amdgcn_mfma_f32_16x16x32_bf16(a[kc], bU[s][kc], acc[ct][s], 0, 0, 0);
    }
}

// ---------------------------------------------------------------------------
// Fused: GEMM mega-phase + climb d9..d4 + (last block per tree) inline tail.
// LDS 144KB pool; inline tail reuses dead regions with dedicated layout.
__global__ __launch_bounds__(512, 1) void fused6_k(const float* __restrict__ F,
                                                   const uint16_t* __restrict__ WT,
                                                   const float* __restrict__ biasS,
                                                   const uint16_t* __restrict__ UT,
                                                   float* __restrict__ h,
                                                   float* __restrict__ c,
                                                   int* __restrict__ ctr) {
    __shared__ __align__(16) char SM[147456];
    uint16_t* FINT = (uint16_t*)SM;
    uint16_t* FLS  = (uint16_t*)(SM + 16384);
    uint16_t* BNC  = (uint16_t*)(SM + 32768);
    uint16_t* HA   = (uint16_t*)(SM + 98304);
    float*    CA   = (float*)(SM + 114688);
    uint16_t* H9   = (uint16_t*)SM;               // FINT dead after G
    float*    C9v  = (float*)(SM + 16384);        // FLS dead after G
    uint16_t* H8   = (uint16_t*)(SM + 32768);     // BNC dead after bnc_rd
    float*    C8   = (float*)(SM + 40960);
    uint16_t* H7   = (uint16_t*)(SM + 49152);
    float*    C7   = (float*)(SM + 57344);
    uint16_t* H6   = (uint16_t*)(SM + 65536);
    float*    C6   = (float*)(SM + 73728);
    uint16_t* H5   = (uint16_t*)(SM + 81920);
    float*    C5   = (float*)(SM + 90112);

    const int tid = threadIdx.x;
    const int w = tid >> 6, lane = tid & 63, q = lane >> 4, l15 = lane & 15;
    const int colf = w * 16 + l15;
    const int colb = w * 16 + q * 4;
    const int tree = blockIdx.x >> 4;
    const int pos4 = blockIdx.x & 15;
    const int vbase = tree * MTREE;
    const int v4 = vbase + 15 + pos4;
    const int v5 = vbase + 31 + 2 * pos4;
    const int v6 = vbase + 63 + 4 * pos4;
    const int v7 = vbase + 127 + 8 * pos4;
    const int v8 = vbase + 255 + 16 * pos4;
    const int v9 = vbase + 511 + 32 * pos4;
    const int vL = vbase + 1023 + 64 * pos4;

    auto fint_node = [&](int row) -> int {
        if (row < 32) return v9 + row;
        if (row < 48) return v8 + row - 32;
        if (row < 56) return v7 + row - 48;
        if (row < 60) return v6 + row - 56;
        if (row < 62) return v5 + row - 60;
        return v4;                       // rows 62,63 (63 = dummy dup)
    };

    // (1) issue FINT global loads
    const int srow = tid >> 4, scx = tid & 15;
    float4 i0[2], i1[2];
#pragma unroll
    for (int t = 0; t < 2; ++t) {
        int ci = t * 512 + tid;
        int row = ci >> 4, cx = ci & 15;
        const float* src = F + (size_t)fint_node(row) * 128 + cx * 8;
        i0[t] = *(const float4*)src;
        i1[t] = *(const float4*)(src + 4);
    }
    // (2) issue leaf F loads
    const float* sa = F + (size_t)(vL + srow) * 128 + scx * 8;
    const float* sb = F + (size_t)(vL + 32 + srow) * 128 + scx * 8;
    float4 a0 = *(const float4*)sa, a1 = *(const float4*)(sa + 4);
    float4 b0 = *(const float4*)sb, b1 = *(const float4*)(sb + 4);

    // (3) W weights + bias (L2-warm)
    bf16x8 aW[4][4];
    float4 bias4[4];
#pragma unroll
    for (int s = 0; s < 4; ++s) {
        int row = (w + s * 8) * 16 + l15;
#pragma unroll
        for (int kc = 0; kc < 4; ++kc)
            aW[s][kc] = *(const bf16x8*)(WT + (size_t)row * 128 + kc * 32 + q * 8);
        bias4[s] = *(const float4*)(biasS + (w + s * 8) * 16 + q * 4);
    }

    // (4) pack FINT + FLS -> LDS
#pragma unroll
    for (int t = 0; t < 2; ++t) {
        int ci = t * 512 + tid;
        int row = ci >> 4, cx = ci & 15;
        *(uint4*)&FINT[SWZ(row, cx)] = pack_bf8(i0[t], i1[t]);
    }
    *(uint4*)&FLS[SWZ(srow, scx)]      = pack_bf8(a0, a1);
    *(uint4*)&FLS[SWZ(32 + srow, scx)] = pack_bf8(b0, b1);
    lds_barrier();                                     // BAR 1

    // ---- G: barrier-free GEMM mega-phase ----
    auto wx_tile = [&](int baseRow) {
        bf16x8 b[4];
#pragma unroll
        for (int kc = 0; kc < 4; ++kc)
            b[kc] = *(const bf16x8*)&FINT[SWZ(baseRow + l15, kc * 4 + q)];
        f32x4 acc[4] = {};
#pragma unroll
        for (int s = 0; s < 4; ++s)
#pragma unroll
            for (int kc = 0; kc < 4; ++kc)
                acc[s] = __builtin_amdgcn_mfma_f32_16x16x32_bf16(aW[s][kc], b[kc], acc[s], 0, 0, 0);
        int n = baseRow + l15;
#pragma unroll
        for (int r = 0; r < 4; ++r) {
            uint2 g;
            g.x = cvtpk(acc[0][r] + bias4[0][r], acc[1][r] + bias4[1][r]);
            g.y = cvtpk(acc[2][r] + bias4[2][r], acc[3][r] + bias4[3][r]);
            int f = colb + r;
            *(uint2*)&BNC[n * 512 + ((f ^ (n & 15)) << 2)] = g;
        }
    };
    wx_tile(0);
    wx_tile(16);
    wx_tile(32);
    wx_tile(48);

    // leaf GEMM + leaf epilogue
#pragma unroll
    for (int nt = 0; nt < 4; ++nt) {
        bf16x8 b[4];
#pragma unroll
        for (int kc = 0; kc < 4; ++kc)
            b[kc] = *(const bf16x8*)&FLS[SWZ(nt * 16 + l15, kc * 4 + q)];
        f32x4 acc[4] = {};
#pragma unroll
        for (int s = 0; s < 4; ++s)
#pragma unroll
            for (int kc = 0; kc < 4; ++kc)
                acc[s] = __builtin_amdgcn_mfma_f32_16x16x32_bf16(aW[s][kc], b[kc], acc[s], 0, 0, 0);

        int row = nt * 16 + l15;
        float cv[4], hv[4];
#pragma unroll
        for (int r = 0; r < 4; ++r) {
            float pi = acc[0][r] + bias4[0][r];
            float po = acc[1][r] + bias4[1][r];
            float pu = acc[2][r] + bias4[2][r];
            float cn = sigmoidf_(pi) * tanhf_(pu);
            cv[r] = cn;
            hv[r] = sigmoidf_(po) * tanhf_(cn);
        }
        *(float4*)&h[(size_t)(vL + row) * 128 + colb] = *(float4*)hv;
        int chunk = colb >> 3, within = colb & 7;
        uint2 hp;
        hp.x = cvtpk(hv[0], hv[1]);
        hp.y = cvtpk(hv[2], hv[3]);
        *(uint2*)&HA[row * 128 + ((chunk ^ (row & 7)) * 8) + within] = hp;
        *(float4*)&CA[CAX(row, colb)] = *(float4*)cv;
    }
    bf16x8 bU[4][4];
    load_bU(UT, bU);
    lds_barrier();                                     // BAR 2

    // ---- read all wx from bounce ----
    auto bnc_rd = [&](int n, float o[4]) {
        wx_unpack(*(const ushort4*)&BNC[n * 512 + ((colf ^ (n & 15)) << 2)], o);
    };
    float wxA[4][2][4], wxB[2][2][4], wxC[2][4], wxD[2][4], wxE[2][4], wxFp[2][4];
#pragma unroll
    for (int ct = 0; ct < 4; ++ct)
#pragma unroll
        for (int j = 0; j < 2; ++j)
            bnc_rd(ct * 8 + q * 2 + j, wxA[ct][j]);
#pragma unroll
    for (int ct = 0; ct < 2; ++ct)
#pragma unroll
        for (int j = 0; j < 2; ++j)
            bnc_rd(32 + ct * 8 + q * 2 + j, wxB[ct][j]);
#pragma unroll
    for (int j = 0; j < 2; ++j) {
        int pl = q * 2 + j;
        bnc_rd(48 + pl, wxC[j]);
        bnc_rd(56 + (pl & 3), wxD[j]);
        bnc_rd(60 + (pl & 1), wxE[j]);
        bnc_rd(62, wxFp[j]);
    }

    // ---- LEVEL A (d9) ----
    {
        f32x4 acc[4][4] = {};
        matvec_lds<4>(HA, bU, acc, l15, q);
#pragma unroll
        for (int ct = 0; ct < 4; ++ct) {
            float cch[4];
#pragma unroll
            for (int r = 0; r < 4; ++r)
                cch[r] = CA[CAX(ct * 16 + q * 4 + r, colf)];
            float hv[2], cn[2];
            gate_epi(acc[ct], wxA[ct], cch, hv, cn);
#pragma unroll
            for (int j = 0; j < 2; ++j) {
                int pl = ct * 8 + q * 2 + j;
                h[(size_t)(v9 + pl) * 128 + colf] = hv[j];
                hwr(H9, pl, colf, hv[j]);
                C9v[CIDX(pl, colf)] = cn[j];
            }
        }
    }
    lds_barrier();                                     // BAR 3

    // ---- LEVEL B (d8) ----
    {
        float cch[2][4];
#pragma unroll
        for (int ct = 0; ct < 2; ++ct)
#pragma unroll
            for (int r = 0; r < 4; ++r)
                cch[ct][r] = C9v[CIDX(ct * 16 + q * 4 + r, colf)];
        f32x4 acc[2][4] = {};
        matvec_lds<2>(H9, bU, acc, l15, q);
#pragma unroll
        for (int ct = 0; ct < 2; ++ct) {
            float hv[2], cn[2];
            gate_epi(acc[ct], wxB[ct], cch[ct], hv, cn);
#pragma unroll
            for (int j = 0; j < 2; ++j) {
                int pl = ct * 8 + q * 2 + j;
                h[(size_t)(v8 + pl) * 128 + colf] = hv[j];
                hwr(H8, pl, colf, hv[j]);
                C8[CIDX(pl, colf)] = cn[j];
            }
        }
    }
    lds_barrier();                                     // BAR 4

    // ---- LEVEL C (d7) ----
    {
        float cch[4];
#pragma unroll
        for (int r = 0; r < 4; ++r)
            cch[r] = C8[CIDX(q * 4 + r, colf)];
        f32x4 acc[1][4] = {};
        matvec_lds<1>(H8, bU, acc, l15, q);
        float hv[2], cn[2];
        gate_epi(acc[0], wxC, cch, hv, cn);
#pragma unroll
        for (int j = 0; j < 2; ++j) {
            int pl = q * 2 + j;
            h[(size_t)(v7 + pl) * 128 + colf] = hv[j];
            hwr(H7, pl, colf, hv[j]);
            C7[CIDX(pl, colf)] = cn[j];
        }
    }
    lds_barrier();                                     // BAR 5

    // ---- LEVEL D (d6) ----
    {
        float cch[4];
#pragma unroll
        for (int r = 0; r < 4; ++r)
            cch[r] = C7[CIDX(q * 4 + r, colf)];
        f32x4 acc[1][4] = {};
        matvec_lds<1>(H7, bU, acc, l15, q);
        float hv[2], cn[2];
        gate_epi(acc[0], wxD, cch, hv, cn);
#pragma unroll
        for (int j = 0; j < 2; ++j) {
            int pl = q * 2 + j;
            if (pl < 4) {
                h[(size_t)(v6 + pl) * 128 + colf] = hv[j];
                hwr(H6, pl, colf, hv[j]);
                C6[CIDX(pl, colf)] = cn[j];
            }
        }
    }
    lds_barrier();                                     // BAR 6

    // ---- LEVEL E (d5) ----
    {
        float cch[4];
#pragma unroll
        for (int r = 0; r < 4; ++r)
            cch[r] = C6[CIDX(q * 4 + r, colf)];
        f32x4 acc[1][4] = {};
        matvec_lds<1>(H6, bU, acc, l15, q);
        float hv[2], cn[2];
        gate_epi(acc[0], wxE, cch, hv, cn);
#pragma unroll
        for (int j = 0; j < 2; ++j) {
            int pl = q * 2 + j;
            if (pl < 2) {
                h[(size_t)(v5 + pl) * 128 + colf] = hv[j];
                hwr(H5, pl, colf, hv[j]);
                C5[CIDX(pl, colf)] = cn[j];
            }
        }
    }
    lds_barrier();                                     // BAR 7

    // ---- LEVEL F (d4): global h + compact c ----
    {
        float cch[4];
#pragma unroll
        for (int r = 0; r < 4; ++r)
            cch[r] = C5[CIDX(q * 4 + r, colf)];
        f32x4 acc[1][4] = {};
        matvec_lds<1>(H5, bU, acc, l15, q);
        float hv[2], cn[2];
        gate_epi(acc[0], wxFp, cch, hv, cn);
        if (q == 0) {
            h[(size_t)v4 * 128 + colf] = hv[0];
            c[(size_t)blockIdx.x * 128 + colf] = cn[0];
        }
    }

    // ======== last-block-per-tree: run this tree's tail inline ========
    __threadfence();                                   // release (all threads)
    lds_barrier();
    int* flag = (int*)(SM + 147448);
    if (tid == 0) *flag = (atomicAdd(&ctr[tree], 1) == 15) ? 1 : 0;
    lds_barrier();
    if (*flag == 0) return;
    __threadfence();                                   // acquire

    // dedicated dead-region layout for the tail
    uint16_t* FINTt = (uint16_t*)SM;                   // [0,4K)
    uint16_t* BNCt  = (uint16_t*)(SM + 32768);         // [32K,48K)
    uint16_t* Hbuf  = (uint16_t*)(SM + 49152);         // [48K,60K) 48 rows
    float*    CS    = (float*)(SM + 65536);            // [64K,81K)

    const int vb = vbase;
    auto tnode = [&](int row) -> int {
        if (row < 8) return vb + 7 + row;
        if (row < 12) return vb + 3 + (row - 8);
        if (row < 14) return vb + 1 + (row - 12);
        return vb;
    };

    // issue loads: internal F rows, d4 h rows, compact d4 c
    float4 fi0, fi1, hh0, hh1;
    if (tid < 256) {
        int row = tid >> 4, cx = tid & 15;
        const float* fsrc = F + (size_t)tnode(row) * 128 + cx * 8;
        fi0 = *(const float4*)fsrc;
        fi1 = *(const float4*)(fsrc + 4);
        const float* hsrc = h + (size_t)(vb + 15 + row) * 128 + cx * 8;
        hh0 = *(const float4*)hsrc;
        hh1 = *(const float4*)(hsrc + 4);
    }
    float cgl[4];
#pragma unroll
    for (int r = 0; r < 4; ++r) {
        int cl = q * 4 + r;
        cgl[r] = c[(size_t)(tree * 16 + cl) * 128 + colf];
    }

    // pack FINTt + Hbuf (dedicated regions -> one barrier)
    if (tid < 256) {
        int row = tid >> 4, cx = tid & 15;
        *(uint4*)&FINTt[SWZ(row, cx)] = pack_bf8(fi0, fi1);
        *(uint4*)&Hbuf[SWZ(row, cx)] = pack_bf8(hh0, hh1);
    }
    lds_barrier();

    // phase W: one GEMM tile -> BNCt
    {
        bf16x8 b[4];
#pragma unroll
        for (int kc = 0; kc < 4; ++kc)
            b[kc] = *(const bf16x8*)&FINTt[SWZ(l15, kc * 4 + q)];
        f32x4 acc[4] = {};
#pragma unroll
        for (int s = 0; s < 4; ++s)
#pragma unroll
            for (int kc = 0; kc < 4; ++kc)
                acc[s] = __builtin_amdgcn_mfma_f32_16x16x32_bf16(aW[s][kc], b[kc], acc[s], 0, 0, 0);
        int n = l15;
#pragma unroll
        for (int r = 0; r < 4; ++r) {
            uint2 g;
            g.x = cvtpk(acc[0][r] + bias4[0][r], acc[1][r] + bias4[1][r]);
            g.y = cvtpk(acc[2][r] + bias4[2][r], acc[3][r] + bias4[3][r]);
            int f = colb + r;
            *(uint2*)&BNCt[n * 512 + ((f ^ (n & 15)) << 2)] = g;
        }
    }
    lds_barrier();

    float wx1[2][4], wx2[2][4], wx3[2][4], wx4p[2][4];
#pragma unroll
    for (int j = 0; j < 2; ++j) {
        int pl = q * 2 + j;
        wx_unpack(*(const ushort4*)&BNCt[pl * 512 + ((colf ^ (pl & 15)) << 2)], wx1[j]);
        int n2 = 8 + (pl & 3);
        wx_unpack(*(const ushort4*)&BNCt[n2 * 512 + ((colf ^ (n2 & 15)) << 2)], wx2[j]);
        int n3 = 12 + (pl & 1);
        wx_unpack(*(const ushort4*)&BNCt[n3 * 512 + ((colf ^ (n3 & 15)) << 2)], wx3[j]);
        wx_unpack(*(const ushort4*)&BNCt[14 * 512 + ((colf ^ 14) << 2)], wx4p[j]);
    }

    // G1: d3, 8 parents (children = d4 rows 0..15)
    {
        f32x4 acc[1][4] = {};
        matvec_lds<1>(Hbuf, bU, acc, l15, q);
        float hv[2], cn[2];
        gate_epi(acc[0], wx1, cgl, hv, cn);
#pragma unroll
        for (int j = 0; j < 2; ++j) {
            int pl = q * 2 + j;
            h[(size_t)(vb + 7 + pl) * 128 + colf] = hv[j];
            hwr(Hbuf, 16 + pl, colf, hv[j]);
            CS[pl * 132 + colf] = cn[j];
        }
    }
    lds_barrier();

    // G2: d2, 4 parents
    {
        float cch[4];
#pragma unroll
        for (int r = 0; r < 4; ++r)
            cch[r] = CS[(q * 4 + r) * 132 + colf];
        f32x4 acc[1][4] = {};
        matvec_lds<1>(&Hbuf[16 * 128], bU, acc, l15, q);
        float hv[2], cn[2];
        gate_epi(acc[0], wx2, cch, hv, cn);
#pragma unroll
        for (int j = 0; j < 2; ++j) {
            int pl = q * 2 + j;
            if (pl < 4) {
                h[(size_t)(vb + 3 + pl) * 128 + colf] = hv[j];
                hwr(Hbuf, 32 + pl, colf, hv[j]);
                CS[(16 + pl) * 132 + colf] = cn[j];
            }
        }
    }
    lds_barrier();

    // G3: d1, 2 parents
    {
        float cch[4];
#pragma unroll
        for (int r = 0; r < 4; ++r)
            cch[r] = CS[(16 + q * 4 + r) * 132 + colf];
        f32x4 acc[1][4] = {};
        matvec_lds<1>(&Hbuf[32 * 128], bU, acc, l15, q);
        float hv[2], cn[2];
        gate_epi(acc[0], wx3, cch, hv, cn);
#pragma unroll
        for (int j = 0; j < 2; ++j) {
            int pl = q * 2 + j;
            if (pl < 2) {
                h[(size_t)(vb + 1 + pl) * 128 + colf] = hv[j];
                hwr(Hbuf, 40 + pl, colf, hv[j]);
                CS[(16 + pl) * 132 + colf] = cn[j];
            }
        }
    }
    lds_barrier();

    // G4: d0, root
    {
        float cch[4];
#pragma unroll
        for (int r = 0; r < 4; ++r)
            cch[r] = CS[(16 + q * 4 + r) * 132 + colf];
        f32x4 acc[1][4] = {};
        matvec_lds<1>(&Hbuf[40 * 128], bU, acc, l15, q);
        float hv[2], cn[2];
        gate_epi(acc[0], wx4p, cch, hv, cn);
        if (q == 0) {
            h[(size_t)vb * 128 + colf] = hv[0];
        }
    }
}

// ---------------------------------------------------------------------------
extern "C" void kernel_launch(void* const* d_in, const int* in_sizes, int n_in,
                              void* d_out, int out_size, void* d_ws, size_t ws_size,
                              hipStream_t stream) {
    const float* features = (const float*)d_in[0];
    const float* W_iou    = (const float*)d_in[1];
    const float* b_iou    = (const float*)d_in[2];
    const float* U_iou    = (const float*)d_in[3];
    const float* W_f      = (const float*)d_in[4];
    const float* b_f      = (const float*)d_in[5];
    const float* U_f      = (const float*)d_in[6];
    float* h = (float*)d_out;

    char* wp = (char*)d_ws;
    float*    c     = (float*)wp;    wp += 512 * 128 * 4;      // d4 rows only
    uint16_t* WT    = (uint16_t*)wp; wp += 512 * 128 * 2;
    uint16_t* UT    = (uint16_t*)wp; wp += 512 * 128 * 2;
    float*    biasS = (float*)wp;    wp += 512 * 4;
    int*      ctr   = (int*)wp;      wp += NTREES * sizeof(int);

    hipLaunchKernelGGL(prep_k, dim3(1025), dim3(128), 0, stream,
                       W_iou, W_f, U_iou, U_f, b_iou, b_f, WT, UT, biasS, ctr);
    hipLaunchKernelGGL(fused6_k, dim3(512), dim3(512), 0, stream,
                       features, WT, biasS, UT, h, c, ctr);
}